// Round 2
// baseline (166.483 us; speedup 1.0000x reference)
//
#include <hip/hip_runtime.h>
#include <math.h>

// Problem constants (match reference)
#define BATCH 1024
#define NV    64      // N_VARS
#define MC    256     // M_CLAUSES
#define KD    12      // K_DIM
#define PI_F  3.14159265358979323846f

// ws/LDS layout (floats):
//   NR rows 64x68: row q = C-row of var v = nv(q) = (q+1)%64+1, slot j =
//     C[v][j+1], with cols {v-2, v-1, v} (wrapped in 1..64) PRE-ZEROED.
//   c0N[64]  at C0OFF : C[v][0]
//   DgA[64]  at DGAOFF: DgA[v-1] = C[v][prev1(v)]  (prev1(1)=64)
//   DgB[64]  at DGBOFF: DgB[v-1] = C[v][prev2(v)]  (prev2(1)=63, prev2(2)=64)
#define CBUF   4544
#define C0OFF  4352
#define DGAOFF 4416
#define DGBOFF 4480

typedef float f2 __attribute__((ext_vector_type(2)));
typedef float v4f __attribute__((ext_vector_type(4)));

// ---- DPP add helpers (intrinsic form: bound_ctrl=true, old=0 -> the
// canonical GCNDPPCombine-fusable pattern; compiler inserts required DPP
// hazard wait-states). 0xB1 qp xor1, 0x4E qp xor2, 0x124 row_ror:4,
// 0x128 row_ror:8, 0x142 row_bcast15, 0x143 row_bcast31.
template <int CTRL>
__device__ __forceinline__ float dpp_addf(float x) {
  int y = __builtin_amdgcn_update_dpp(0, __float_as_int(x), CTRL, 0xF, 0xF, true);
  return x + __int_as_float(y);
}
__device__ __forceinline__ float allreduce16(float x) {
  x = dpp_addf<0xB1>(x);
  x = dpp_addf<0x4E>(x);
  x = dpp_addf<0x124>(x);
  x = dpp_addf<0x128>(x);
  return x;
}
__device__ __forceinline__ float readlane63(float x) {
  return __int_as_float(__builtin_amdgcn_readlane(__float_as_int(x), 63));
}

// Pin a loaded 128-bit value into VGPRs: the volatile asm is a scheduling
// anchor the ds_read must feed, so prefetch loads cannot be sunk into their
// uses (round-0's VGPR_Count=40 proved the compiler was doing exactly that,
// exposing ~120cy LDS latency per group at the point of use).
__device__ __forceinline__ void pin(v4f& x) { asm volatile("" : "+v"(x)); }

// ---- Kernel 1: Gram rows (pre-zeroed excl. columns) + c0/dgA/dgB tables ----
__global__ void compute_C_kernel(const float* __restrict__ S,
                                 const float* __restrict__ w,
                                 float* __restrict__ Cg, int nsplit) {
  const int q = blockIdx.x;
  const int mc = blockIdx.y;
  const int j = threadIdx.x;  // column 0..64
  if (j > NV) return;
  const int v = (q + 1) % 64 + 1;
  const int mlen = MC / nsplit;
  const int m0 = mc * mlen;
  float a0 = 0.f, a1 = 0.f, a2 = 0.f, a3 = 0.f;
  for (int m = m0; m < m0 + mlen; m += 4) {
    const float w0 = w[m], w1 = w[m + 1], w2 = w[m + 2], w3 = w[m + 3];
    a0 = fmaf(S[(m + 0) * (NV + 1) + v] * w0 * w0, S[(m + 0) * (NV + 1) + j], a0);
    a1 = fmaf(S[(m + 1) * (NV + 1) + v] * w1 * w1, S[(m + 1) * (NV + 1) + j], a1);
    a2 = fmaf(S[(m + 2) * (NV + 1) + v] * w2 * w2, S[(m + 2) * (NV + 1) + j], a2);
    a3 = fmaf(S[(m + 3) * (NV + 1) + v] * w3 * w3, S[(m + 3) * (NV + 1) + j], a3);
  }
  const float acc = (a0 + a1) + (a2 + a3);
  float* buf = Cg + mc * CBUF;
  const int p1 = (v == 1) ? 64 : (v - 1);
  const int p2 = (v == 1) ? 63 : (v == 2) ? 64 : (v - 2);
  if (j == 0) buf[C0OFF + q] = acc;
  if (j == p1) buf[DGAOFF + (v - 1)] = acc;
  if (j == p2) buf[DGBOFF + (v - 1)] = acc;
  if (j > 0) {
    // pre-zero the columns Phase B must exclude: {v-2, v-1, v}
    const float st = (j == v || j == p1 || j == p2) ? 0.f : acc;
    buf[q * 68 + (j - 1)] = st;
  }
}

// ---- Kernel 2: two-column-deferred mixing, packed-fp32 k-pairs -------------
// Block = 256 thr = 4 waves = 4 batches, shared LDS C. Wave: kq = l>>4 owns
// k-triple {3kq..3kq+2}; n16 = l&15 owns vars 4*n16+1..4*n16+4.
// Per lane: V01[4] (f2: k0,k1) + V2[4] (k2). Carried: P01/P2 = Q_i (dot
// missing cols i-1,i-2), vp1*/vp2* = u_{i-1}/u_{i-2}.
// Step i: B) Q_{i+1} from pre-zeroed row via v_pk_fma_f32 (8 slots vs 12);
// A) g = P + DgA*vp1 + DgB*vp2 (pk) -> norm chain -> v_new; C) delayed
// writeback of u_{i-1}. DPP hops act on the pair's subregisters in place.
__global__ __launch_bounds__(256, 1) void mixing_kernel(
    const float* __restrict__ z, const float* __restrict__ r,
    const float* __restrict__ Cg, const int* __restrict__ max_iter_p,
    float* __restrict__ out, int nsplit) {
  __shared__ float Ls[CBUF];  // 18176 B

  const int t = threadIdx.x;
  const int l = t & 63;
  const int kq = l >> 4;
  const int n16 = l & 15;
  const int b = blockIdx.x * 4 + (t >> 6);
  const int max_iter = max_iter_p[0];

  // stage (and m-split-reduce) C into LDS
  {
    const float4* src = (const float4*)Cg;
    float4* dst = (float4*)Ls;
    for (int idx = t; idx < CBUF / 4; idx += 256) {
      float4 a = src[idx];
      for (int u = 1; u < nsplit; ++u) {
        const float4 p = src[u * (CBUF / 4) + idx];
        a.x += p.x; a.y += p.y; a.z += p.z; a.w += p.w;
      }
      dst[idx] = a;
    }
  }

  const float row0 = (kq == 0) ? 1.f : 0.f;

  // ---- init: V[n] = -cos(pi z) e0 + sin(pi z) * r_perp_hat ----
  f2 V01[4];
  float V2[4];
  #pragma unroll
  for (int s = 0; s < 4; ++s) {
    const int n = 4 * n16 + s;
    const float zv = z[b * NV + n];
    float rp[3];
    float ssp = 0.f;
    #pragma unroll
    for (int j = 0; j < 3; ++j) {
      const int k = 3 * kq + j;
      rp[j] = (k == 0) ? 0.f : r[(b * NV + n) * KD + k];
      ssp = fmaf(rp[j], rp[j], ssp);
    }
    ssp += __shfl_xor(ssp, 16, 64);
    ssp += __shfl_xor(ssp, 32, 64);
    const float inv = 1.f / fmaxf(sqrtf(ssp), 1e-8f);
    float sn, cs;
    sincosf(PI_F * zv, &sn, &cs);
    float vv[3];
    #pragma unroll
    for (int j = 0; j < 3; ++j) {
      const int k = 3 * kq + j;
      vv[j] = (k == 0) ? -cs : sn * rp[j] * inv;
    }
    V01[s].x = vv[0];
    V01[s].y = vv[1];
    V2[s] = vv[2];
  }

  __syncthreads();

  f2 P01, vp1_01, vp2_01;
  float P2, vp1_2, vp2_2;

  // ---- prologue: Q_1 from pre-zeroed row NR[63] (= C[1]);
  //      vp1 = V_init[var64] (slot63), vp2 = V_init[var63] (slot62) ----
  {
    const v4f ce = *(const v4f*)&Ls[63 * 68 + 4 * n16];
    const float c0 = Ls[C0OFF + 63];
    f2 q01 = ce.x * V01[0];
    float q2 = ce.x * V2[0];
    q01 = __builtin_elementwise_fma((f2){ce.y, ce.y}, V01[1], q01);
    q2 = fmaf(ce.y, V2[1], q2);
    q01 = __builtin_elementwise_fma((f2){ce.z, ce.z}, V01[2], q01);
    q2 = fmaf(ce.z, V2[2], q2);
    q01 = __builtin_elementwise_fma((f2){ce.w, ce.w}, V01[3], q01);
    q2 = fmaf(ce.w, V2[3], q2);
    q01.x = allreduce16(q01.x);
    q01.y = allreduce16(q01.y);
    q2 = allreduce16(q2);
    q01.x = fmaf(row0, c0, q01.x);
    P01 = q01; P2 = q2;
    const int src = l | 15;  // this row's lane 15
    vp1_01.x = __shfl(V01[3].x, src, 64);
    vp1_01.y = __shfl(V01[3].y, src, 64);
    vp1_2    = __shfl(V2[3],    src, 64);
    vp2_01.x = __shfl(V01[2].x, src, 64);
    vp2_01.y = __shfl(V01[2].y, src, 64);
    vp2_2    = __shfl(V2[2],    src, 64);
  }

  v4f cbA[4], cbB[4], c0A, c0B, daA, daB, dbA, dbB;

  // REAL prefetch: loads land in pinned VGPRs at the prefetch point; the
  // following do_group's ~150+ cycles of VALU cover the LDS latency, and
  // the compiler's lgkmcnt wait at first use is then free.
  auto prefetch = [&](v4f cb[4], v4f& c0b, v4f& dab, v4f& dbb, int g) {
    #pragma unroll
    for (int s = 0; s < 4; ++s) {
      cb[s] = *(const v4f*)&Ls[(4 * g + s) * 68 + 4 * n16];
      pin(cb[s]);
    }
    c0b = *(const v4f*)&Ls[C0OFF + 4 * g];
    dab = *(const v4f*)&Ls[DGAOFF + 4 * g];
    dbb = *(const v4f*)&Ls[DGBOFF + 4 * g];
    pin(c0b); pin(dab); pin(dbb);
  };

  auto do_group = [&](int ii, const v4f cb[4], const v4f& c0b,
                      const v4f& dab, const v4f& dbb) {
    const bool own  = (n16 == ii);
    const bool ownP = (n16 == ((ii + 15) & 15));
    #pragma unroll
    for (int s = 0; s < 4; ++s) {
      const v4f ce = cb[s];
      const float db = dbb[s], da = dab[s];

      // ---- Phase A start: the true recurrence (g, n2 partial) ----
      f2 g01 = __builtin_elementwise_fma((f2){db, db}, vp2_01, P01);
      float g2 = fmaf(db, vp2_2, P2);
      g01 = __builtin_elementwise_fma((f2){da, da}, vp1_01, g01);
      g2 = fmaf(da, vp1_2, g2);

      // ---- Phase B products (independent; packed k0k1 + scalar k2) ----
      f2 q01 = ce.x * V01[0];
      float q2 = ce.x * V2[0];
      q01 = __builtin_elementwise_fma((f2){ce.y, ce.y}, V01[1], q01);
      q2 = fmaf(ce.y, V2[1], q2);
      q01 = __builtin_elementwise_fma((f2){ce.z, ce.z}, V01[2], q01);
      q2 = fmaf(ce.z, V2[2], q2);
      q01 = __builtin_elementwise_fma((f2){ce.w, ce.w}, V01[3], q01);
      q2 = fmaf(ce.w, V2[3], q2);

      float n2p = g01.x * g01.x;
      n2p = fmaf(g01.y, g01.y, n2p);
      n2p = fmaf(g2, g2, n2p);

      // ---- cross-lane: A's bcast chain + B's butterflies, hop-major ----
      n2p = dpp_addf<0x142>(n2p);                 // A: row1+=row0, row3+=row2
      q01.x = dpp_addf<0xB1>(q01.x);              // B hop 1
      q01.y = dpp_addf<0xB1>(q01.y);
      q2 = dpp_addf<0xB1>(q2);
      n2p = dpp_addf<0x143>(n2p);                 // A: lane63 = total
      q01.x = dpp_addf<0x4E>(q01.x);              // B hop 2
      q01.y = dpp_addf<0x4E>(q01.y);
      q2 = dpp_addf<0x4E>(q2);
      const float n2 = readlane63(n2p);           // A tail starts
      q01.x = dpp_addf<0x124>(q01.x);             // B hop 3
      q01.y = dpp_addf<0x124>(q01.y);
      q2 = dpp_addf<0x124>(q2);
      const float inv = __builtin_amdgcn_rsqf(fmaxf(n2, 1e-16f));
      q01.x = dpp_addf<0x128>(q01.x);             // B hop 4
      q01.y = dpp_addf<0x128>(q01.y);
      q2 = dpp_addf<0x128>(q2);
      const f2 vn01 = g01 * (f2){-inv, -inv};     // == -g * inv (exact)
      const float vn2 = -g2 * inv;
      q01.x = fmaf(row0, c0b[s], q01.x);          // e0 term -> k=0 only

      // ---- Phase C: delayed writeback of u_{i-1} (held in vp1) ----
      if (s == 0) {
        V01[3].x = ownP ? vp1_01.x : V01[3].x;
        V01[3].y = ownP ? vp1_01.y : V01[3].y;
        V2[3]    = ownP ? vp1_2    : V2[3];
      } else {
        V01[s - 1].x = own ? vp1_01.x : V01[s - 1].x;
        V01[s - 1].y = own ? vp1_01.y : V01[s - 1].y;
        V2[s - 1]    = own ? vp1_2    : V2[s - 1];
      }

      // rotate carried state (renamed by unroll)
      vp2_01 = vp1_01; vp2_2 = vp1_2;
      vp1_01 = vn01;   vp1_2 = vn2;
      P01 = q01;       P2 = q2;
    }
  };

  prefetch(cbA, c0A, daA, dbA, 0);

  // ---- sweeps (groups of 4 steps; ping-pong prefetch, unroll by 2) ----
  for (int it = 0; it < max_iter; ++it) {
    for (int ih = 0; ih < 8; ++ih) {
      prefetch(cbB, c0B, daB, dbB, 2 * ih + 1);
      do_group(2 * ih, cbA, c0A, daA, dbA);
      prefetch(cbA, c0A, daA, dbA, (2 * ih + 2) & 15);
      do_group(2 * ih + 1, cbB, c0B, daB, dbB);
    }
  }

  // final pending writeback: u_64 still in vp1 -> slot 63 (lane 15, V[3])
  {
    const bool l15 = (n16 == 15);
    V01[3].x = l15 ? vp1_01.x : V01[3].x;
    V01[3].y = l15 ? vp1_01.y : V01[3].y;
    V2[3]    = l15 ? vp1_2    : V2[3];
  }

  // ---- epilogue: kq==0 lanes hold k=0 ----
  if (kq == 0) {
    float4 o;
    float* op = &o.x;
    #pragma unroll
    for (int s = 0; s < 4; ++s) {
      float cv = -V01[s].x;
      cv = fminf(fmaxf(cv, -1.f + 1e-6f), 1.f - 1e-6f);
      op[s] = acosf(cv) * (1.f / PI_F);
    }
    ((float4*)(out + b * NV))[n16] = o;
  }
}

extern "C" void kernel_launch(void* const* d_in, const int* in_sizes, int n_in,
                              void* d_out, int out_size, void* d_ws, size_t ws_size,
                              hipStream_t stream) {
  const float* z = (const float*)d_in[0];
  const float* S = (const float*)d_in[1];
  const float* w = (const float*)d_in[2];
  const float* r = (const float*)d_in[3];
  const int* max_iter = (const int*)d_in[4];
  float* Cg = (float*)d_ws;

  const int nsplit = (ws_size >= (size_t)8 * CBUF * 4) ? 8
                   : (ws_size >= (size_t)4 * CBUF * 4) ? 4 : 1;
  compute_C_kernel<<<dim3(NV, nsplit), 128, 0, stream>>>(S, w, Cg, nsplit);
  mixing_kernel<<<BATCH / 4, 256, 0, stream>>>(z, r, Cg, max_iter,
                                               (float*)d_out, nsplit);
}

// Round 3
// 145.475 us; speedup vs baseline: 1.1444x; 1.1444x over previous
//
#include <hip/hip_runtime.h>
#include <math.h>

// Problem constants (match reference)
#define BATCH 1024
#define NV    64      // N_VARS
#define MC    256     // M_CLAUSES
#define KD    12      // K_DIM
#define PI_F  3.14159265358979323846f

// Compact permuted C layout (floats, per m-split copy):
//   rows: 64 x 64. Row q = Gram row of var v = nv(q) = (q+1)%64+1
//     (0-based target jv = (q+1)&63), with 0-based cols {jv, jv-1, jv-2}
//     (wrapped) PRE-ZEROED. Within-row position perm(j0) = (j0&3)*16 + (j0>>2)
//     so lane group jg = l&3 reads a CONTIGUOUS 16-float slice (j0 === jg mod 4).
//   c0N[64]  at C0OFF : c0N[q]   = C[v][0]
//   DgA[64]  at DGAOFF: DgA[v-1] = C[v][prev1(v)]  -> readlane idx i gives C[i][i-1]
//   DgB[64]  at DGBOFF: DgB[v-1] = C[v][prev2(v)]  -> readlane idx i gives C[i][i-2]
#define C0OFF  4096
#define DGAOFF 4160
#define DGBOFF 4224
#define CBUF   4288

typedef float f2  __attribute__((ext_vector_type(2)));
typedef float v4f __attribute__((ext_vector_type(4)));
typedef __attribute__((address_space(3))) float lds_f;

// ---- DPP add helpers (bound_ctrl=true, old=0 -> GCNDPPCombine-fusable) ----
// 0xB1 quad xor1, 0x4E quad xor2, 0x124 row_ror:4, 0x128 row_ror:8,
// 0x142 row_bcast15, 0x143 row_bcast31.
template <int CTRL>
__device__ __forceinline__ float dpp_addf(float x) {
  int y = __builtin_amdgcn_update_dpp(0, __float_as_int(x), CTRL, 0xF, 0xF, true);
  return x + __int_as_float(y);
}
// DPP move (broadcast quad lane QL to whole quad)
template <int CTRL>
__device__ __forceinline__ float dpp_movf(float x) {
  return __int_as_float(
      __builtin_amdgcn_update_dpp(0, __float_as_int(x), CTRL, 0xF, 0xF, true));
}
__device__ __forceinline__ float readlane63(float x) {
  return __int_as_float(__builtin_amdgcn_readlane(__float_as_int(x), 63));
}
__device__ __forceinline__ float rlane(float x, int i) {
  return __int_as_float(__builtin_amdgcn_readlane(__float_as_int(x), i));
}

// Async LDS read: volatile pins the ISSUE point; the compiler does NOT know
// this is a ds_read, so WE provide the counted s_waitcnt + sched_barrier(0)
// before consumption (guide rule #18). Base VGPR + immediate offset -> zero
// per-load address VALU.
template <int IMM>
__device__ __forceinline__ void dsr(v4f& d, unsigned base) {
  asm volatile("ds_read_b128 %0, %1 offset:%2" : "=v"(d) : "v"(base), "i"(IMM));
}

// ---- Kernel 1: Gram rows (permuted, pre-zeroed cols) + c0/dgA/dgB tables ----
__global__ void compute_C_kernel(const float* __restrict__ S,
                                 const float* __restrict__ w,
                                 float* __restrict__ Cg, int nsplit) {
  const int q = blockIdx.x;
  const int mc = blockIdx.y;
  const int j = threadIdx.x;  // column 0..64 (1-based vars; 0 = e0 row)
  if (j > NV) return;
  const int v = (q + 1) % 64 + 1;
  const int mlen = MC / nsplit;
  const int m0 = mc * mlen;
  float a0 = 0.f, a1 = 0.f, a2 = 0.f, a3 = 0.f;
  for (int m = m0; m < m0 + mlen; m += 4) {
    const float w0 = w[m], w1 = w[m + 1], w2 = w[m + 2], w3 = w[m + 3];
    a0 = fmaf(S[(m + 0) * (NV + 1) + v] * w0 * w0, S[(m + 0) * (NV + 1) + j], a0);
    a1 = fmaf(S[(m + 1) * (NV + 1) + v] * w1 * w1, S[(m + 1) * (NV + 1) + j], a1);
    a2 = fmaf(S[(m + 2) * (NV + 1) + v] * w2 * w2, S[(m + 2) * (NV + 1) + j], a2);
    a3 = fmaf(S[(m + 3) * (NV + 1) + v] * w3 * w3, S[(m + 3) * (NV + 1) + j], a3);
  }
  const float acc = (a0 + a1) + (a2 + a3);
  float* buf = Cg + mc * CBUF;
  const int p1 = (v == 1) ? 64 : (v - 1);
  const int p2 = (v == 1) ? 63 : (v == 2) ? 64 : (v - 2);
  if (j == 0) buf[C0OFF + q] = acc;
  if (j == p1) buf[DGAOFF + (v - 1)] = acc;
  if (j == p2) buf[DGBOFF + (v - 1)] = acc;
  if (j > 0) {
    const int j0 = j - 1;  // 0-based var column
    const float st = (j == v || j == p1 || j == p2) ? 0.f : acc;
    buf[q * 64 + (j0 & 3) * 16 + (j0 >> 2)] = st;  // permuted position
  }
}

// ---- Kernel 2: (jg,k)-lane mixing with async row pipeline --------------
// Block = 256 thr = 4 waves = 4 batches, shared LDS C.
// Lane l: jg = l&3 owns vars j0 === jg (mod 4); kk = l>>2 = k-dim (12 of 16).
// Per lane: Vv[8] f2 = V[j0 = jg+8p(+4h)][kk]. Carries P (=Q_i), vp1/vp2
// (u_{i-1},u_{i-2}[kk]). Per step: g = P + da*vp1 + db*vp2 -> n2 reduce
// (ror4,ror8,bcast15,bcast31,readlane63) -> rsq -> vn; Q_{i+1} = 8 pk_fma
// + quad xor1/xor2 reduce + e0 term; delayed writeback of u_{i-1}.
__global__ __launch_bounds__(256, 1) void mixing_kernel(
    const float* __restrict__ z, const float* __restrict__ r,
    const float* __restrict__ Cg, const int* __restrict__ max_iter_p,
    float* __restrict__ out, int nsplit) {
  __shared__ __align__(16) float Ls[CBUF];  // 17152 B

  const int t = threadIdx.x;
  const int l = t & 63;
  const int jg = l & 3;
  const int kk = l >> 2;
  const int b = blockIdx.x * 4 + (t >> 6);
  const int max_iter = max_iter_p[0];

  // stage (and m-split-reduce) compact C into LDS
  {
    const float4* src = (const float4*)Cg;
    float4* dst = (float4*)Ls;
    for (int idx = t; idx < CBUF / 4; idx += 256) {
      float4 a = src[idx];
      for (int u = 1; u < nsplit; ++u) {
        const float4 p = src[u * (CBUF / 4) + idx];
        a.x += p.x; a.y += p.y; a.z += p.z; a.w += p.w;
      }
      dst[idx] = a;
    }
  }

  const float my_e0 = (kk == 0) ? 1.f : 0.f;

  // ---- init: V[j][k] = -cos(pi z_j) [k=0] + sin(pi z_j) * rp_hat[k] ----
  f2 Vv[8];
  #pragma unroll
  for (int p = 0; p < 8; ++p) {
    #pragma unroll
    for (int h = 0; h < 2; ++h) {
      const int j0 = jg + 8 * p + 4 * h;
      const float zv = z[b * NV + j0];
      float rp = 0.f;
      if (kk >= 1 && kk < KD) rp = r[(b * NV + j0) * KD + kk];
      float ssp = rp * rp;
      ssp += __shfl_xor(ssp, 4, 64);
      ssp += __shfl_xor(ssp, 8, 64);
      ssp += __shfl_xor(ssp, 16, 64);
      ssp += __shfl_xor(ssp, 32, 64);
      const float inv = 1.f / fmaxf(sqrtf(ssp), 1e-8f);
      const float sn = __builtin_amdgcn_sinf(0.5f * zv);  // sin(pi*z)
      const float cs = __builtin_amdgcn_cosf(0.5f * zv);  // cos(pi*z)
      const float vv = (kk == 0) ? -cs : sn * rp * inv;   // kk>=12 -> 0
      if (h) Vv[p].y = vv; else Vv[p].x = vv;
    }
  }

  __syncthreads();

  // lane-distributed tables: lane x holds c0N[x], DgA[x], DgB[x]
  const float t0v = Ls[C0OFF + l];
  const float t1v = Ls[DGAOFF + l];
  const float t2v = Ls[DGBOFF + l];

  float P, vp1, vp2;

  // ---- prologue: Q_0-target from row 63; vp1/vp2 = V_init[63/62][kk] ----
  {
    const int rb = 63 * 64 + jg * 16;
    const v4f c0r = *(const v4f*)&Ls[rb + 0];
    const v4f c1r = *(const v4f*)&Ls[rb + 4];
    const v4f c2r = *(const v4f*)&Ls[rb + 8];
    const v4f c3r = *(const v4f*)&Ls[rb + 12];
    f2 qa = (f2){c0r.x, c0r.y} * Vv[0];
    qa = __builtin_elementwise_fma((f2){c0r.z, c0r.w}, Vv[1], qa);
    qa = __builtin_elementwise_fma((f2){c2r.x, c2r.y}, Vv[4], qa);
    qa = __builtin_elementwise_fma((f2){c2r.z, c2r.w}, Vv[5], qa);
    f2 qb = (f2){c1r.x, c1r.y} * Vv[2];
    qb = __builtin_elementwise_fma((f2){c1r.z, c1r.w}, Vv[3], qb);
    qb = __builtin_elementwise_fma((f2){c3r.x, c3r.y}, Vv[6], qb);
    qb = __builtin_elementwise_fma((f2){c3r.z, c3r.w}, Vv[7], qb);
    const f2 qs = qa + qb;
    float q = qs.x + qs.y;
    q = dpp_addf<0xB1>(q);
    q = dpp_addf<0x4E>(q);
    q = fmaf(my_e0, Ls[C0OFF + 63], q);
    P = q;
    // j0=63 -> (jg=3, p=7, h=1); j0=62 -> (jg=2, p=7, h=1)
    vp1 = dpp_movf<0xFF>(Vv[7].y);  // quad bcast lane 3
    vp2 = dpp_movf<0xAA>(Vv[7].y);  // quad bcast lane 2
  }

  // LDS byte base for this lane's row slice (includes jg*64B)
  const unsigned lbase = (unsigned)(unsigned long long)(lds_f*)&Ls[jg * 16];

  v4f Rb[16];  // 4-row register ring, all indices compile-time

#define PFROW(R) \
  dsr<((((R) & 63) * 256) + 0)>(Rb[(((R) & 3) * 4) + 0], lbase); \
  dsr<((((R) & 63) * 256) + 16)>(Rb[(((R) & 3) * 4) + 1], lbase); \
  dsr<((((R) & 63) * 256) + 32)>(Rb[(((R) & 3) * 4) + 2], lbase); \
  dsr<((((R) & 63) * 256) + 48)>(Rb[(((R) & 3) * 4) + 3], lbase);

#define STEPF(I) { \
  constexpr int i_ = (I); \
  constexpr int j0w_ = (i_ + 63) & 63; \
  constexpr int p_ = j0w_ >> 3; \
  constexpr int h_ = (j0w_ >> 2) & 1; \
  constexpr int jgo_ = j0w_ & 3; \
  constexpr int s_ = (i_ & 3) * 4; \
  /* rows <= i_ landed after this wait; rows i_+1..i_+2 stay in flight */ \
  asm volatile("s_waitcnt lgkmcnt(8)" ::: "memory"); \
  __builtin_amdgcn_sched_barrier(0); \
  PFROW(i_ + 3) \
  const float da_ = rlane(t1v, i_); \
  const float db_ = rlane(t2v, i_); \
  const float c0_ = rlane(t0v, i_); \
  const float g_ = fmaf(da_, vp1, fmaf(db_, vp2, P)); \
  float t_ = g_ * g_; \
  f2 qa_ = (f2){Rb[s_ + 0].x, Rb[s_ + 0].y} * Vv[0]; \
  qa_ = __builtin_elementwise_fma((f2){Rb[s_ + 0].z, Rb[s_ + 0].w}, Vv[1], qa_); \
  t_ = dpp_addf<0x124>(t_); \
  qa_ = __builtin_elementwise_fma((f2){Rb[s_ + 2].x, Rb[s_ + 2].y}, Vv[4], qa_); \
  qa_ = __builtin_elementwise_fma((f2){Rb[s_ + 2].z, Rb[s_ + 2].w}, Vv[5], qa_); \
  t_ = dpp_addf<0x128>(t_); \
  f2 qb_ = (f2){Rb[s_ + 1].x, Rb[s_ + 1].y} * Vv[2]; \
  qb_ = __builtin_elementwise_fma((f2){Rb[s_ + 1].z, Rb[s_ + 1].w}, Vv[3], qb_); \
  t_ = dpp_addf<0x142>(t_); \
  qb_ = __builtin_elementwise_fma((f2){Rb[s_ + 3].x, Rb[s_ + 3].y}, Vv[6], qb_); \
  qb_ = __builtin_elementwise_fma((f2){Rb[s_ + 3].z, Rb[s_ + 3].w}, Vv[7], qb_); \
  t_ = dpp_addf<0x143>(t_); \
  const f2 qs_ = qa_ + qb_; \
  float q_ = qs_.x + qs_.y; \
  const float n2_ = readlane63(t_); \
  const float inv_ = __builtin_amdgcn_rsqf(fmaxf(n2_, 1e-16f)); \
  q_ = dpp_addf<0xB1>(q_); \
  q_ = dpp_addf<0x4E>(q_); \
  const float vn_ = -g_ * inv_; \
  q_ = fmaf(my_e0, c0_, q_); \
  if constexpr (h_) { Vv[p_].y = (jg == jgo_) ? vp1 : Vv[p_].y; } \
  else              { Vv[p_].x = (jg == jgo_) ? vp1 : Vv[p_].x; } \
  vp2 = vp1; vp1 = vn_; P = q_; \
}

#define S4(N) STEPF((N) + 0) STEPF((N) + 1) STEPF((N) + 2) STEPF((N) + 3)
#define S16(N) S4((N) + 0) S4((N) + 4) S4((N) + 8) S4((N) + 12)

  // drain prologue LDS traffic so lgkm counts are ours alone
  asm volatile("s_waitcnt lgkmcnt(0)" ::: "memory");
  __builtin_amdgcn_sched_barrier(0);
  PFROW(0) PFROW(1) PFROW(2)  // 12 in flight (peak 12 <= 15 HW limit)

  #pragma unroll 1
  for (int it = 0; it < max_iter; ++it) {
    S16(0) S16(16) S16(32) S16(48)
  }

  // final pending writeback: u_63 in vp1 -> col 63 (jg==3, Vv[7].y)
  Vv[7].y = (jg == 3) ? vp1 : Vv[7].y;

  // ---- epilogue: transpose k=0 slice via LDS (C is dead), coalesced out ----
  __syncthreads();
  {
    float* Lw = Ls + (t >> 6) * 64;
    if (kk == 0) {
      Lw[jg +  0] = Vv[0].x; Lw[jg +  4] = Vv[0].y;
      Lw[jg +  8] = Vv[1].x; Lw[jg + 12] = Vv[1].y;
      Lw[jg + 16] = Vv[2].x; Lw[jg + 20] = Vv[2].y;
      Lw[jg + 24] = Vv[3].x; Lw[jg + 28] = Vv[3].y;
      Lw[jg + 32] = Vv[4].x; Lw[jg + 36] = Vv[4].y;
      Lw[jg + 40] = Vv[5].x; Lw[jg + 44] = Vv[5].y;
      Lw[jg + 48] = Vv[6].x; Lw[jg + 52] = Vv[6].y;
      Lw[jg + 56] = Vv[7].x; Lw[jg + 60] = Vv[7].y;
    }
    float cv = -Lw[l];
    cv = fminf(fmaxf(cv, -1.f + 1e-6f), 1.f - 1e-6f);
    out[b * NV + l] = acosf(cv) * (1.f / PI_F);
  }
}

extern "C" void kernel_launch(void* const* d_in, const int* in_sizes, int n_in,
                              void* d_out, int out_size, void* d_ws, size_t ws_size,
                              hipStream_t stream) {
  const float* z = (const float*)d_in[0];
  const float* S = (const float*)d_in[1];
  const float* w = (const float*)d_in[2];
  const float* r = (const float*)d_in[3];
  const int* max_iter = (const int*)d_in[4];
  float* Cg = (float*)d_ws;

  const int nsplit = (ws_size >= (size_t)8 * CBUF * 4) ? 8
                   : (ws_size >= (size_t)4 * CBUF * 4) ? 4 : 1;
  compute_C_kernel<<<dim3(NV, nsplit), 128, 0, stream>>>(S, w, Cg, nsplit);
  mixing_kernel<<<BATCH / 4, 256, 0, stream>>>(z, r, Cg, max_iter,
                                               (float*)d_out, nsplit);
}

// Round 4
// 141.580 us; speedup vs baseline: 1.1759x; 1.0275x over previous
//
#include <hip/hip_runtime.h>
#include <math.h>

// Problem constants (match reference)
#define BATCH 1024
#define NV    64      // N_VARS
#define MC    256     // M_CLAUSES
#define KD    12      // K_DIM
#define PI_F  3.14159265358979323846f

// Compact permuted C layout (floats, per m-split copy):
//   rows: 64 x 64. Row q = Gram row of var v = nv(q) = (q+1)%64+1
//     (0-based target jv = (q+1)&63), with 0-based cols {jv, jv-1, jv-2}
//     (wrapped) PRE-ZEROED. Within-row position perm(j0) = (j0&3)*16 + (j0>>2)
//     so lane group jg = l&3 reads a CONTIGUOUS 16-float slice (j0 === jg mod 4).
//   c0N[64]  at C0OFF : c0N[q]   = C[v][0]
//   DgA[64]  at DGAOFF: DgA[v-1] = C[v][prev1(v)]  -> readlane idx i gives C[i][i-1]
//   DgB[64]  at DGBOFF: DgB[v-1] = C[v][prev2(v)]  -> readlane idx i gives C[i][i-2]
#define C0OFF  4096
#define DGAOFF 4160
#define DGBOFF 4224
#define CBUF   4288

typedef float f2  __attribute__((ext_vector_type(2)));
typedef float v4f __attribute__((ext_vector_type(4)));
typedef __attribute__((address_space(3))) float lds_f;

// ---- DPP add helpers (bound_ctrl=true, old=0 -> GCNDPPCombine-fusable) ----
// 0xB1 quad xor1, 0x4E quad xor2, 0x124 row_ror:4, 0x128 row_ror:8,
// 0x142 row_bcast15, 0x143 row_bcast31.
template <int CTRL>
__device__ __forceinline__ float dpp_addf(float x) {
  int y = __builtin_amdgcn_update_dpp(0, __float_as_int(x), CTRL, 0xF, 0xF, true);
  return x + __int_as_float(y);
}
// DPP move (broadcast quad lane QL to whole quad)
template <int CTRL>
__device__ __forceinline__ float dpp_movf(float x) {
  return __int_as_float(
      __builtin_amdgcn_update_dpp(0, __float_as_int(x), CTRL, 0xF, 0xF, true));
}
__device__ __forceinline__ float readlane63(float x) {
  return __int_as_float(__builtin_amdgcn_readlane(__float_as_int(x), 63));
}
__device__ __forceinline__ float rlane(float x, int i) {
  return __int_as_float(__builtin_amdgcn_readlane(__float_as_int(x), i));
}

// Async LDS read: volatile pins the ISSUE point and keeps mutual order with
// the counted s_waitcnt asms; base VGPR + immediate offset -> zero per-load
// address VALU. The consume-side ordering is carried by REGISTER deps on the
// waitcnt asm ("+v" on the slot), NOT by a memory clobber / sched_barrier --
// this is the round-4 change that lets the scheduler fill the chain-tail
// bubbles with neighboring steps' independent product work.
template <int IMM>
__device__ __forceinline__ void dsr(v4f& d, unsigned base) {
  asm volatile("ds_read_b128 %0, %1 offset:%2" : "=v"(d) : "v"(base), "i"(IMM));
}

// ---- Kernel 1: Gram rows (permuted, pre-zeroed cols) + c0/dgA/dgB tables ----
__global__ void compute_C_kernel(const float* __restrict__ S,
                                 const float* __restrict__ w,
                                 float* __restrict__ Cg, int nsplit) {
  const int q = blockIdx.x;
  const int mc = blockIdx.y;
  const int j = threadIdx.x;  // column 0..64 (1-based vars; 0 = e0 row)
  if (j > NV) return;
  const int v = (q + 1) % 64 + 1;
  const int mlen = MC / nsplit;
  const int m0 = mc * mlen;
  float a0 = 0.f, a1 = 0.f, a2 = 0.f, a3 = 0.f;
  for (int m = m0; m < m0 + mlen; m += 4) {
    const float w0 = w[m], w1 = w[m + 1], w2 = w[m + 2], w3 = w[m + 3];
    a0 = fmaf(S[(m + 0) * (NV + 1) + v] * w0 * w0, S[(m + 0) * (NV + 1) + j], a0);
    a1 = fmaf(S[(m + 1) * (NV + 1) + v] * w1 * w1, S[(m + 1) * (NV + 1) + j], a1);
    a2 = fmaf(S[(m + 2) * (NV + 1) + v] * w2 * w2, S[(m + 2) * (NV + 1) + j], a2);
    a3 = fmaf(S[(m + 3) * (NV + 1) + v] * w3 * w3, S[(m + 3) * (NV + 1) + j], a3);
  }
  const float acc = (a0 + a1) + (a2 + a3);
  float* buf = Cg + mc * CBUF;
  const int p1 = (v == 1) ? 64 : (v - 1);
  const int p2 = (v == 1) ? 63 : (v == 2) ? 64 : (v - 2);
  if (j == 0) buf[C0OFF + q] = acc;
  if (j == p1) buf[DGAOFF + (v - 1)] = acc;
  if (j == p2) buf[DGBOFF + (v - 1)] = acc;
  if (j > 0) {
    const int j0 = j - 1;  // 0-based var column
    const float st = (j == v || j == p1 || j == p2) ? 0.f : acc;
    buf[q * 64 + (j0 & 3) * 16 + (j0 >> 2)] = st;  // permuted position
  }
}

// ---- Kernel 2: (jg,k)-lane mixing with async row pipeline, fence-free ----
// Block = 256 thr = 4 waves = 4 batches, shared LDS C.
// Lane l: jg = l&3 owns vars j0 === jg (mod 4); kk = l>>2 = k-dim (12 of 16).
// Per lane: Vv[8] f2 = V[j0 = jg+8p(+4h)][kk]. Carries P (=Q_i), vp1/vp2
// (u_{i-1},u_{i-2}[kk]). Serial chain per step: vn_{i-1} -> g -> g^2 ->
// 4 DPP hops -> readlane63 -> rsq -> vn_i (~70cy). All other work (8 pk_fma
// products, q-hops, writeback, prefetch) is independent of the last two
// chains (pre-zeroed cols) and is left free for the scheduler to pack into
// the chain bubbles, including ACROSS step boundaries.
__global__ __launch_bounds__(256, 1) void mixing_kernel(
    const float* __restrict__ z, const float* __restrict__ r,
    const float* __restrict__ Cg, const int* __restrict__ max_iter_p,
    float* __restrict__ out, int nsplit) {
  __shared__ __align__(16) float Ls[CBUF];  // 17152 B

  const int t = threadIdx.x;
  const int l = t & 63;
  const int jg = l & 3;
  const int kk = l >> 2;
  const int b = blockIdx.x * 4 + (t >> 6);
  const int max_iter = max_iter_p[0];

  // stage (and m-split-reduce) compact C into LDS
  {
    const float4* src = (const float4*)Cg;
    float4* dst = (float4*)Ls;
    for (int idx = t; idx < CBUF / 4; idx += 256) {
      float4 a = src[idx];
      for (int u = 1; u < nsplit; ++u) {
        const float4 p = src[u * (CBUF / 4) + idx];
        a.x += p.x; a.y += p.y; a.z += p.z; a.w += p.w;
      }
      dst[idx] = a;
    }
  }

  const float my_e0 = (kk == 0) ? 1.f : 0.f;

  // ---- init: V[j][k] = -cos(pi z_j) [k=0] + sin(pi z_j) * rp_hat[k] ----
  f2 Vv[8];
  #pragma unroll
  for (int p = 0; p < 8; ++p) {
    #pragma unroll
    for (int h = 0; h < 2; ++h) {
      const int j0 = jg + 8 * p + 4 * h;
      const float zv = z[b * NV + j0];
      float rp = 0.f;
      if (kk >= 1 && kk < KD) rp = r[(b * NV + j0) * KD + kk];
      float ssp = rp * rp;
      ssp += __shfl_xor(ssp, 4, 64);
      ssp += __shfl_xor(ssp, 8, 64);
      ssp += __shfl_xor(ssp, 16, 64);
      ssp += __shfl_xor(ssp, 32, 64);
      const float inv = 1.f / fmaxf(sqrtf(ssp), 1e-8f);
      const float sn = __builtin_amdgcn_sinf(0.5f * zv);  // sin(pi*z)
      const float cs = __builtin_amdgcn_cosf(0.5f * zv);  // cos(pi*z)
      const float vv = (kk == 0) ? -cs : sn * rp * inv;   // kk>=12 -> 0
      if (h) Vv[p].y = vv; else Vv[p].x = vv;
    }
  }

  __syncthreads();

  // lane-distributed tables: lane x holds c0N[x], DgA[x], DgB[x]
  const float t0v = Ls[C0OFF + l];
  const float t1v = Ls[DGAOFF + l];
  const float t2v = Ls[DGBOFF + l];

  float P, vp1, vp2;

  // ---- prologue: Q_0-target from row 63; vp1/vp2 = V_init[63/62][kk] ----
  {
    const int rb = 63 * 64 + jg * 16;
    const v4f c0r = *(const v4f*)&Ls[rb + 0];
    const v4f c1r = *(const v4f*)&Ls[rb + 4];
    const v4f c2r = *(const v4f*)&Ls[rb + 8];
    const v4f c3r = *(const v4f*)&Ls[rb + 12];
    f2 qa = (f2){c0r.x, c0r.y} * Vv[0];
    qa = __builtin_elementwise_fma((f2){c0r.z, c0r.w}, Vv[1], qa);
    qa = __builtin_elementwise_fma((f2){c2r.x, c2r.y}, Vv[4], qa);
    qa = __builtin_elementwise_fma((f2){c2r.z, c2r.w}, Vv[5], qa);
    f2 qb = (f2){c1r.x, c1r.y} * Vv[2];
    qb = __builtin_elementwise_fma((f2){c1r.z, c1r.w}, Vv[3], qb);
    qb = __builtin_elementwise_fma((f2){c3r.x, c3r.y}, Vv[6], qb);
    qb = __builtin_elementwise_fma((f2){c3r.z, c3r.w}, Vv[7], qb);
    const f2 qs = qa + qb;
    float q = qs.x + qs.y;
    q = dpp_addf<0xB1>(q);
    q = dpp_addf<0x4E>(q);
    q = fmaf(my_e0, Ls[C0OFF + 63], q);
    P = q;
    // j0=63 -> (jg=3, p=7, h=1); j0=62 -> (jg=2, p=7, h=1)
    vp1 = dpp_movf<0xFF>(Vv[7].y);  // quad bcast lane 3
    vp2 = dpp_movf<0xAA>(Vv[7].y);  // quad bcast lane 2
  }

  // LDS byte base for this lane's row slice (includes jg*64B)
  const unsigned lbase = (unsigned)(unsigned long long)(lds_f*)&Ls[jg * 16];

  v4f Rb[16];  // 4-row register ring, all indices compile-time

#define PFROW(R) \
  dsr<((((R) & 63) * 256) + 0)>(Rb[(((R) & 3) * 4) + 0], lbase); \
  dsr<((((R) & 63) * 256) + 16)>(Rb[(((R) & 3) * 4) + 1], lbase); \
  dsr<((((R) & 63) * 256) + 32)>(Rb[(((R) & 3) * 4) + 2], lbase); \
  dsr<((((R) & 63) * 256) + 48)>(Rb[(((R) & 3) * 4) + 3], lbase);

// Counted wait expressed through REGISTER deps: consumers of the slot are
// ordered after the wait by the "+v" outputs; no memory clobber, no
// sched_barrier -> everything else schedules freely across steps.
#define WAITR(SL) \
  asm volatile("s_waitcnt lgkmcnt(8)" \
               : "+v"(Rb[(SL) * 4 + 0]), "+v"(Rb[(SL) * 4 + 1]), \
                 "+v"(Rb[(SL) * 4 + 2]), "+v"(Rb[(SL) * 4 + 3]));

#define STEPF(I) { \
  constexpr int i_ = (I); \
  constexpr int j0w_ = (i_ + 63) & 63; \
  constexpr int p_ = j0w_ >> 3; \
  constexpr int h_ = (j0w_ >> 2) & 1; \
  constexpr int jgo_ = j0w_ & 3; \
  constexpr int s_ = (i_ & 3) * 4; \
  /* rows <= i_ landed after this wait; rows i_+1..i_+2 stay in flight */ \
  WAITR(i_ & 3) \
  PFROW(i_ + 3) \
  const float da_ = rlane(t1v, i_); \
  const float db_ = rlane(t2v, i_); \
  const float c0_ = rlane(t0v, i_); \
  const float g_ = fmaf(da_, vp1, fmaf(db_, vp2, P)); \
  float t_ = g_ * g_; \
  f2 qa_ = (f2){Rb[s_ + 0].x, Rb[s_ + 0].y} * Vv[0]; \
  qa_ = __builtin_elementwise_fma((f2){Rb[s_ + 0].z, Rb[s_ + 0].w}, Vv[1], qa_); \
  t_ = dpp_addf<0x124>(t_); \
  f2 qb_ = (f2){Rb[s_ + 1].x, Rb[s_ + 1].y} * Vv[2]; \
  qb_ = __builtin_elementwise_fma((f2){Rb[s_ + 1].z, Rb[s_ + 1].w}, Vv[3], qb_); \
  t_ = dpp_addf<0x128>(t_); \
  qa_ = __builtin_elementwise_fma((f2){Rb[s_ + 2].x, Rb[s_ + 2].y}, Vv[4], qa_); \
  qa_ = __builtin_elementwise_fma((f2){Rb[s_ + 2].z, Rb[s_ + 2].w}, Vv[5], qa_); \
  t_ = dpp_addf<0x142>(t_); \
  qb_ = __builtin_elementwise_fma((f2){Rb[s_ + 3].x, Rb[s_ + 3].y}, Vv[6], qb_); \
  qb_ = __builtin_elementwise_fma((f2){Rb[s_ + 3].z, Rb[s_ + 3].w}, Vv[7], qb_); \
  t_ = dpp_addf<0x143>(t_); \
  const float n2_ = readlane63(t_); \
  /* chain tail shadow: q-finish, e0 term, writeback all independent */ \
  const f2 qs_ = qa_ + qb_; \
  float q_ = qs_.x + qs_.y; \
  q_ = dpp_addf<0xB1>(q_); \
  const float inv_ = __builtin_amdgcn_rsqf(fmaxf(n2_, 1e-16f)); \
  q_ = dpp_addf<0x4E>(q_); \
  q_ = fmaf(my_e0, c0_, q_); \
  if constexpr (h_) { Vv[p_].y = (jg == jgo_) ? vp1 : Vv[p_].y; } \
  else              { Vv[p_].x = (jg == jgo_) ? vp1 : Vv[p_].x; } \
  const float vn_ = -g_ * inv_; \
  vp2 = vp1; vp1 = vn_; P = q_; \
}

#define S4(N) STEPF((N) + 0) STEPF((N) + 1) STEPF((N) + 2) STEPF((N) + 3)
#define S16(N) S4((N) + 0) S4((N) + 4) S4((N) + 8) S4((N) + 12)

  // drain prologue LDS traffic so lgkm counts are ours alone
  asm volatile("s_waitcnt lgkmcnt(0)" ::: "memory");
  PFROW(0) PFROW(1) PFROW(2)  // 12 in flight (peak 12 <= 15 HW limit)

  #pragma unroll 1
  for (int it = 0; it < max_iter; ++it) {
    S16(0) S16(16) S16(32) S16(48)
  }

  // final pending writeback: u_63 in vp1 -> col 63 (jg==3, Vv[7].y)
  Vv[7].y = (jg == 3) ? vp1 : Vv[7].y;

  // ---- epilogue: transpose k=0 slice via LDS (C is dead), coalesced out ----
  // (__syncthreads' lgkmcnt(0) drain also retires the ring's tail reads.)
  __syncthreads();
  {
    float* Lw = Ls + (t >> 6) * 64;
    if (kk == 0) {
      Lw[jg +  0] = Vv[0].x; Lw[jg +  4] = Vv[0].y;
      Lw[jg +  8] = Vv[1].x; Lw[jg + 12] = Vv[1].y;
      Lw[jg + 16] = Vv[2].x; Lw[jg + 20] = Vv[2].y;
      Lw[jg + 24] = Vv[3].x; Lw[jg + 28] = Vv[3].y;
      Lw[jg + 32] = Vv[4].x; Lw[jg + 36] = Vv[4].y;
      Lw[jg + 40] = Vv[5].x; Lw[jg + 44] = Vv[5].y;
      Lw[jg + 48] = Vv[6].x; Lw[jg + 52] = Vv[6].y;
      Lw[jg + 56] = Vv[7].x; Lw[jg + 60] = Vv[7].y;
    }
    float cv = -Lw[l];
    cv = fminf(fmaxf(cv, -1.f + 1e-6f), 1.f - 1e-6f);
    out[b * NV + l] = acosf(cv) * (1.f / PI_F);
  }
}

extern "C" void kernel_launch(void* const* d_in, const int* in_sizes, int n_in,
                              void* d_out, int out_size, void* d_ws, size_t ws_size,
                              hipStream_t stream) {
  const float* z = (const float*)d_in[0];
  const float* S = (const float*)d_in[1];
  const float* w = (const float*)d_in[2];
  const float* r = (const float*)d_in[3];
  const int* max_iter = (const int*)d_in[4];
  float* Cg = (float*)d_ws;

  const int nsplit = (ws_size >= (size_t)8 * CBUF * 4) ? 8
                   : (ws_size >= (size_t)4 * CBUF * 4) ? 4 : 1;
  compute_C_kernel<<<dim3(NV, nsplit), 128, 0, stream>>>(S, w, Cg, nsplit);
  mixing_kernel<<<BATCH / 4, 256, 0, stream>>>(z, r, Cg, max_iter,
                                               (float*)d_out, nsplit);
}